// Round 1
// baseline (39.844 us; speedup 1.0000x reference)
//
#include <hip/hip_runtime.h>
#include <math.h>

#define MAX_COV 10000.0f
#define MIN_COV 0.0001f
#define SYMM_THRESH 1e-05f
#define DET_THRESH 1e-06f
#define MAX_POS 1000.0f
#define EIG_CLAMP 0.0001f
#define INV_EPS 0.0001f

namespace {
constexpr int BS = 256;

__device__ __forceinline__ void eigvals3(
    float m00, float m01, float m02, float m11, float m12, float m22,
    float& l1, float& l2, float& l3)
{
    const float q   = (m00 + m11 + m22) * (1.0f / 3.0f);
    const float b00 = m00 - q, b11 = m11 - q, b22 = m22 - q;
    const float offsq = m01 * m01 + m02 * m02 + m12 * m12;
    const float p2  = b00 * b00 + b11 * b11 + b22 * b22 + 2.0f * offsq;
    const float p   = sqrtf(p2 * (1.0f / 6.0f));
    const float detB =
          b00 * (b11 * b22 - m12 * m12)
        - m01 * (m01 * b22 - m12 * m02)
        + m02 * (m01 * m12 - b11 * m02);
    const float pinv = 1.0f / fmaxf(p, 1e-30f);
    float r = 0.5f * detB * pinv * pinv * pinv;
    r = fminf(1.0f, fmaxf(-1.0f, r));
    const float phi = acosf(r) * (1.0f / 3.0f);
    l1 = q + 2.0f * p * cosf(phi);
    l3 = q + 2.0f * p * cosf(phi + 2.0943951023931953f); // + 2*pi/3
    l2 = 3.0f * q - l1 - l3;
}

__global__ __launch_bounds__(BS)
void wl_kernel(const float* __restrict__ miu1, const float* __restrict__ miu2,
               const float* __restrict__ cov1, const float* __restrict__ cov2,
               float* __restrict__ out, int N)
{
    __shared__ float s_a[BS * 9];
    __shared__ float s_b[BS * 9];
    __shared__ float s_m1[BS * 3];
    __shared__ float s_m2[BS * 3];

    const int tid  = threadIdx.x;
    const int base = blockIdx.x * BS;
    const int nb   = min(BS, N - base);

    const float* c1p = cov1 + (size_t)base * 9;
    const float* c2p = cov2 + (size_t)base * 9;
    const float* m1p = miu1 + (size_t)base * 3;
    const float* m2p = miu2 + (size_t)base * 3;

    for (int j = tid; j < nb * 9; j += BS) { s_a[j] = c1p[j]; s_b[j] = c2p[j]; }
    for (int j = tid; j < nb * 3; j += BS) { s_m1[j] = m1p[j]; s_m2[j] = m2p[j]; }
    __syncthreads();

    float wout[9];
    float mv[3];

    if (tid < nb) {
        float c1[9], c2r[9];
        #pragma unroll
        for (int k = 0; k < 9; ++k) { c1[k] = s_a[tid * 9 + k]; c2r[k] = s_b[tid * 9 + k]; }
        float u1[3], u2[3];
        #pragma unroll
        for (int k = 0; k < 3; ++k) { u1[k] = s_m1[tid * 3 + k]; u2[k] = s_m2[tid * 3 + k]; }

        // ---- stability mask (strict comparisons; NaN/Inf fail automatically) ----
        bool ok = true;
        #pragma unroll
        for (int k = 0; k < 9; ++k) {
            float a = fabsf(c1[k]), b = fabsf(c2r[k]);
            ok = ok && (a < MAX_COV) && (a > MIN_COV) && (b < MAX_COV) && (b > MIN_COV);
        }
        ok = ok && (fabsf(c1[1] - c1[3]) < SYMM_THRESH)
                && (fabsf(c1[2] - c1[6]) < SYMM_THRESH)
                && (fabsf(c1[5] - c1[7]) < SYMM_THRESH);
        ok = ok && (fabsf(c2r[1] - c2r[3]) < SYMM_THRESH)
                && (fabsf(c2r[2] - c2r[6]) < SYMM_THRESH)
                && (fabsf(c2r[5] - c2r[7]) < SYMM_THRESH);
        const float det1 = c1[0] * (c1[4] * c1[8] - c1[5] * c1[7])
                         - c1[1] * (c1[3] * c1[8] - c1[5] * c1[6])
                         + c1[2] * (c1[3] * c1[7] - c1[4] * c1[6]);
        const float det2 = c2r[0] * (c2r[4] * c2r[8] - c2r[5] * c2r[7])
                         - c2r[1] * (c2r[3] * c2r[8] - c2r[5] * c2r[6])
                         + c2r[2] * (c2r[3] * c2r[7] - c2r[4] * c2r[6]);
        ok = ok && (fabsf(det1) > DET_THRESH) && (fabsf(det2) > DET_THRESH);
        #pragma unroll
        for (int k = 0; k < 3; ++k)
            ok = ok && (fabsf(u1[k]) < MAX_POS) && (fabsf(u2[k]) < MAX_POS);

        // masked items -> identity (outputs zeroed at the end, like the reference)
        #pragma unroll
        for (int k = 0; k < 9; ++k) {
            const float idv = (k == 0 || k == 4 || k == 8) ? 1.0f : 0.0f;
            c1[k]  = ok ? c1[k]  : idv;
            c2r[k] = ok ? c2r[k] : idv;
        }

        // M1 = symmetrize(c1)
        const float m00 = c1[0];
        const float m01 = 0.5f * (c1[1] + c1[3]);
        const float m02 = 0.5f * (c1[2] + c1[6]);
        const float m11 = c1[4];
        const float m12 = 0.5f * (c1[5] + c1[7]);
        const float m22 = c1[8];

        float l1, l2, l3;
        eigvals3(m00, m01, m02, m11, m12, m22, l1, l2, l3);
        l1 = fmaxf(l1, EIG_CLAMP); l2 = fmaxf(l2, EIG_CLAMP); l3 = fmaxf(l3, EIG_CLAMP);
        const float sa = sqrtf(l1), sb = sqrtf(l2), sc = sqrtf(l3);
        const float i_ab = 1.0f / (sa + sb);
        const float i_bc = 1.0f / (sb + sc);
        const float i_ac = 1.0f / (sa + sc);
        // Newton-form coefficients for f=sqrt at nodes (l1,l2,l3)
        const float q0 = sa, q1 = i_ab, q2 = -i_ab * i_bc * i_ac;
        // and for f = 1/(INV_EPS + sqrt)
        const float ea = 1.0f / (INV_EPS + sa);
        const float eb = 1.0f / (INV_EPS + sb);
        const float ec = 1.0f / (INV_EPS + sc);
        const float g0 = ea;
        const float g1 = -ea * eb * i_ab;
        const float g2 = (INV_EPS + sa + sb + sc) * ea * eb * ec * i_ab * i_bc * i_ac;

        // U = M - l1*I, V = M - l2*I, P = U*V (symmetric since U,V commute)
        const float u00 = m00 - l1, u11 = m11 - l1, u22 = m22 - l1;
        const float v00 = m00 - l2, v11 = m11 - l2, v22 = m22 - l2;
        const float P00 = u00 * v00 + m01 * m01 + m02 * m02;
        const float P01 = u00 * m01 + m01 * v11 + m02 * m12;
        const float P02 = u00 * m02 + m01 * m12 + m02 * v22;
        const float P11 = m01 * m01 + u11 * v11 + m12 * m12;
        const float P12 = m01 * m02 + u11 * m12 + m12 * v22;
        const float P22 = m02 * m02 + m12 * m12 + u22 * v22;

        // A_sqrt (S), A_sqrt_inv (G), both symmetric
        const float S00 = q0 + q1 * u00 + q2 * P00;
        const float S01 =      q1 * m01 + q2 * P01;
        const float S02 =      q1 * m02 + q2 * P02;
        const float S11 = q0 + q1 * u11 + q2 * P11;
        const float S12 =      q1 * m12 + q2 * P12;
        const float S22 = q0 + q1 * u22 + q2 * P22;

        const float G00 = g0 + g1 * u00 + g2 * P00;
        const float G01 =      g1 * m01 + g2 * P01;
        const float G02 =      g1 * m02 + g2 * P02;
        const float G11 = g0 + g1 * u11 + g2 * P11;
        const float G12 =      g1 * m12 + g2 * P12;
        const float G22 = g0 + g1 * u22 + g2 * P22;

        // C = symmetrize(S * c2 * S)
        float T[9];
        T[0] = S00 * c2r[0] + S01 * c2r[3] + S02 * c2r[6];
        T[1] = S00 * c2r[1] + S01 * c2r[4] + S02 * c2r[7];
        T[2] = S00 * c2r[2] + S01 * c2r[5] + S02 * c2r[8];
        T[3] = S01 * c2r[0] + S11 * c2r[3] + S12 * c2r[6];
        T[4] = S01 * c2r[1] + S11 * c2r[4] + S12 * c2r[7];
        T[5] = S01 * c2r[2] + S11 * c2r[5] + S12 * c2r[8];
        T[6] = S02 * c2r[0] + S12 * c2r[3] + S22 * c2r[6];
        T[7] = S02 * c2r[1] + S12 * c2r[4] + S22 * c2r[7];
        T[8] = S02 * c2r[2] + S12 * c2r[5] + S22 * c2r[8];
        float Cf[9];
        Cf[0] = T[0] * S00 + T[1] * S01 + T[2] * S02;
        Cf[1] = T[0] * S01 + T[1] * S11 + T[2] * S12;
        Cf[2] = T[0] * S02 + T[1] * S12 + T[2] * S22;
        Cf[3] = T[3] * S00 + T[4] * S01 + T[5] * S02;
        Cf[4] = T[3] * S01 + T[4] * S11 + T[5] * S12;
        Cf[5] = T[3] * S02 + T[4] * S12 + T[5] * S22;
        Cf[6] = T[6] * S00 + T[7] * S01 + T[8] * S02;
        Cf[7] = T[6] * S01 + T[7] * S11 + T[8] * S12;
        Cf[8] = T[6] * S02 + T[7] * S12 + T[8] * S22;
        const float C00 = Cf[0];
        const float C01 = 0.5f * (Cf[1] + Cf[3]);
        const float C02 = 0.5f * (Cf[2] + Cf[6]);
        const float C11 = Cf[4];
        const float C12 = 0.5f * (Cf[5] + Cf[7]);
        const float C22 = Cf[8];

        // C_sqrt: f(lambda) = sqrt(|lambda|) = (lambda^2)^0.25
        float e1, e2, e3;
        eigvals3(C00, C01, C02, C11, C12, C22, e1, e2, e3);
        const float ra = sqrtf(fabsf(e1));
        const float rb = sqrtf(fabsf(e2));
        const float rc = sqrtf(fabsf(e3));
        const float j_ab = 1.0f / fmaxf(ra + rb, 1e-12f);
        const float j_bc = 1.0f / fmaxf(rb + rc, 1e-12f);
        const float j_ac = 1.0f / fmaxf(ra + rc, 1e-12f);
        const float h0 = ra, h1 = j_ab, h2 = -j_ab * j_bc * j_ac;
        const float cu00 = C00 - e1, cu11 = C11 - e1, cu22 = C22 - e1;
        const float cv00 = C00 - e2, cv11 = C11 - e2, cv22 = C22 - e2;
        const float R00 = cu00 * cv00 + C01 * C01 + C02 * C02;
        const float R01 = cu00 * C01 + C01 * cv11 + C02 * C12;
        const float R02 = cu00 * C02 + C01 * C12 + C02 * cv22;
        const float R11 = C01 * C01 + cu11 * cv11 + C12 * C12;
        const float R12 = C01 * C02 + cu11 * C12 + C12 * cv22;
        const float R22 = C02 * C02 + C12 * C12 + cu22 * cv22;

        const float X00 = h0 + h1 * cu00 + h2 * R00;
        const float X01 =      h1 * C01  + h2 * R01;
        const float X02 =      h1 * C02  + h2 * R02;
        const float X11 = h0 + h1 * cu11 + h2 * R11;
        const float X12 =      h1 * C12  + h2 * R12;
        const float X22 = h0 + h1 * cu22 + h2 * R22;

        // W = S * X * G
        float T2[9];
        T2[0] = S00 * X00 + S01 * X01 + S02 * X02;
        T2[1] = S00 * X01 + S01 * X11 + S02 * X12;
        T2[2] = S00 * X02 + S01 * X12 + S02 * X22;
        T2[3] = S01 * X00 + S11 * X01 + S12 * X02;
        T2[4] = S01 * X01 + S11 * X11 + S12 * X12;
        T2[5] = S01 * X02 + S11 * X12 + S12 * X22;
        T2[6] = S02 * X00 + S12 * X01 + S22 * X02;
        T2[7] = S02 * X01 + S12 * X11 + S22 * X12;
        T2[8] = S02 * X02 + S12 * X12 + S22 * X22;
        float W[9];
        W[0] = T2[0] * G00 + T2[1] * G01 + T2[2] * G02;
        W[1] = T2[0] * G01 + T2[1] * G11 + T2[2] * G12;
        W[2] = T2[0] * G02 + T2[1] * G12 + T2[2] * G22;
        W[3] = T2[3] * G00 + T2[4] * G01 + T2[5] * G02;
        W[4] = T2[3] * G01 + T2[4] * G11 + T2[5] * G12;
        W[5] = T2[3] * G02 + T2[4] * G12 + T2[5] * G22;
        W[6] = T2[6] * G00 + T2[7] * G01 + T2[8] * G02;
        W[7] = T2[6] * G01 + T2[7] * G11 + T2[8] * G12;
        W[8] = T2[6] * G02 + T2[7] * G12 + T2[8] * G22;

        // cov_vel = W + W^T - (cov_1 + cov_1^T);  cov_1 + cov_1^T == 2*M1
        const float M1f[9] = { m00, m01, m02, m01, m11, m12, m02, m12, m22 };
        #pragma unroll
        for (int i = 0; i < 3; ++i)
            #pragma unroll
            for (int j = 0; j < 3; ++j)
                wout[i * 3 + j] = ok ? (W[i * 3 + j] + W[j * 3 + i] - 2.0f * M1f[i * 3 + j])
                                     : 0.0f;
        #pragma unroll
        for (int k = 0; k < 3; ++k) mv[k] = ok ? (u2[k] - u1[k]) : 0.0f;
    }
    __syncthreads();
    if (tid < nb) {
        #pragma unroll
        for (int k = 0; k < 9; ++k) s_a[tid * 9 + k] = wout[k];
        #pragma unroll
        for (int k = 0; k < 3; ++k) s_m1[tid * 3 + k] = mv[k];
    }
    __syncthreads();
    float* out_miu = out;
    float* out_cov = out + (size_t)N * 3;
    for (int j = tid; j < nb * 9; j += BS) out_cov[(size_t)base * 9 + j] = s_a[j];
    for (int j = tid; j < nb * 3; j += BS) out_miu[(size_t)base * 3 + j] = s_m1[j];
}

} // namespace

extern "C" void kernel_launch(void* const* d_in, const int* in_sizes, int n_in,
                              void* d_out, int out_size, void* d_ws, size_t ws_size,
                              hipStream_t stream)
{
    const float* miu1 = (const float*)d_in[0];
    const float* miu2 = (const float*)d_in[1];
    const float* cov1 = (const float*)d_in[2];
    const float* cov2 = (const float*)d_in[3];
    float* out = (float*)d_out;
    const int N = in_sizes[0] / 3;
    const int grid = (N + BS - 1) / BS;
    hipLaunchKernelGGL(wl_kernel, dim3(grid), dim3(BS), 0, stream,
                       miu1, miu2, cov1, cov2, out, N);
}

// Round 2
// 29.722 us; speedup vs baseline: 1.3405x; 1.3405x over previous
//
#include <hip/hip_runtime.h>
#include <math.h>

#define MAX_COV 10000.0f
#define MIN_COV 0.0001f
#define SYMM_THRESH 1e-05f
#define DET_THRESH 1e-06f
#define MAX_POS 1000.0f
#define EIG_CLAMP 0.0001f
#define INV_EPS 0.0001f

namespace {
constexpr int BS = 256;

__device__ __forceinline__ float rcp_fast(float x) {
    return __builtin_amdgcn_rcpf(x);
}

// Closed-form eigenvalues of a symmetric 3x3 (trig method).
// acosf kept at library precision; cos via hardware v_cos_f32 + identity.
__device__ __forceinline__ void eigvals3(
    float m00, float m01, float m02, float m11, float m12, float m22,
    float& l1, float& l2, float& l3)
{
    const float q   = (m00 + m11 + m22) * (1.0f / 3.0f);
    const float b00 = m00 - q, b11 = m11 - q, b22 = m22 - q;
    const float offsq = m01 * m01 + m02 * m02 + m12 * m12;
    const float p2  = b00 * b00 + b11 * b11 + b22 * b22 + 2.0f * offsq;
    const float p   = sqrtf(p2 * (1.0f / 6.0f));
    const float detB =
          b00 * (b11 * b22 - m12 * m12)
        - m01 * (m01 * b22 - m12 * m02)
        + m02 * (m01 * m12 - b11 * m02);
    const float pinv = rcp_fast(fmaxf(p, 1e-30f));
    // Keep left-to-right order: detB==0 (masked identity) must give 0*1e30=0,
    // not 0*inf=NaN. (fmin/fmax clamp would absorb NaN anyway, but be safe.)
    float r = 0.5f * detB;
    r = r * pinv; r = r * pinv; r = r * pinv;
    r = fminf(1.0f, fmaxf(-1.0f, r));
    const float phi = acosf(r) * (1.0f / 3.0f);   // phi in [0, pi/3]
    const float c   = __cosf(phi);                 // hw v_cos_f32
    const float s   = sqrtf(fmaxf(1.0f - c * c, 0.0f)); // sin(phi) >= 0
    l1 = q + 2.0f * p * c;
    // cos(phi + 2pi/3) = -0.5*c - (sqrt(3)/2)*s  ->  l3 = q + p*(-c - sqrt(3)*s)
    l3 = q + p * (-c - 1.7320508075688772f * s);
    l2 = 3.0f * q - l1 - l3;
}

__global__ __launch_bounds__(BS)
void wl_kernel(const float* __restrict__ miu1, const float* __restrict__ miu2,
               const float* __restrict__ cov1, const float* __restrict__ cov2,
               float* __restrict__ out, int N)
{
    const int i = blockIdx.x * BS + threadIdx.x;
    if (i >= N) return;

    float c1[9], c2r[9], u1[3], u2[3];
    {
        const float* p1 = cov1 + (size_t)i * 9;
        const float* p2 = cov2 + (size_t)i * 9;
        #pragma unroll
        for (int k = 0; k < 9; ++k) { c1[k] = p1[k]; c2r[k] = p2[k]; }
        const float* q1p = miu1 + (size_t)i * 3;
        const float* q2p = miu2 + (size_t)i * 3;
        #pragma unroll
        for (int k = 0; k < 3; ++k) { u1[k] = q1p[k]; u2[k] = q2p[k]; }
    }

    // ---- stability mask (strict comparisons; NaN/Inf fail automatically) ----
    bool ok = true;
    #pragma unroll
    for (int k = 0; k < 9; ++k) {
        float a = fabsf(c1[k]), b = fabsf(c2r[k]);
        ok = ok && (a < MAX_COV) && (a > MIN_COV) && (b < MAX_COV) && (b > MIN_COV);
    }
    ok = ok && (fabsf(c1[1] - c1[3]) < SYMM_THRESH)
            && (fabsf(c1[2] - c1[6]) < SYMM_THRESH)
            && (fabsf(c1[5] - c1[7]) < SYMM_THRESH);
    ok = ok && (fabsf(c2r[1] - c2r[3]) < SYMM_THRESH)
            && (fabsf(c2r[2] - c2r[6]) < SYMM_THRESH)
            && (fabsf(c2r[5] - c2r[7]) < SYMM_THRESH);
    const float det1 = c1[0] * (c1[4] * c1[8] - c1[5] * c1[7])
                     - c1[1] * (c1[3] * c1[8] - c1[5] * c1[6])
                     + c1[2] * (c1[3] * c1[7] - c1[4] * c1[6]);
    const float det2 = c2r[0] * (c2r[4] * c2r[8] - c2r[5] * c2r[7])
                     - c2r[1] * (c2r[3] * c2r[8] - c2r[5] * c2r[6])
                     + c2r[2] * (c2r[3] * c2r[7] - c2r[4] * c2r[6]);
    ok = ok && (fabsf(det1) > DET_THRESH) && (fabsf(det2) > DET_THRESH);
    #pragma unroll
    for (int k = 0; k < 3; ++k)
        ok = ok && (fabsf(u1[k]) < MAX_POS) && (fabsf(u2[k]) < MAX_POS);

    // masked items -> identity (outputs zeroed at the end, like the reference)
    #pragma unroll
    for (int k = 0; k < 9; ++k) {
        const float idv = (k == 0 || k == 4 || k == 8) ? 1.0f : 0.0f;
        c1[k]  = ok ? c1[k]  : idv;
        c2r[k] = ok ? c2r[k] : idv;
    }

    // M1 = symmetrize(c1)
    const float m00 = c1[0];
    const float m01 = 0.5f * (c1[1] + c1[3]);
    const float m02 = 0.5f * (c1[2] + c1[6]);
    const float m11 = c1[4];
    const float m12 = 0.5f * (c1[5] + c1[7]);
    const float m22 = c1[8];

    float l1, l2, l3;
    eigvals3(m00, m01, m02, m11, m12, m22, l1, l2, l3);
    l1 = fmaxf(l1, EIG_CLAMP); l2 = fmaxf(l2, EIG_CLAMP); l3 = fmaxf(l3, EIG_CLAMP);
    const float sa = sqrtf(l1), sb = sqrtf(l2), sc = sqrtf(l3);
    const float i_ab = rcp_fast(sa + sb);
    const float i_bc = rcp_fast(sb + sc);
    const float i_ac = rcp_fast(sa + sc);
    // Newton-form coefficients for f=sqrt at nodes (l1,l2,l3)
    const float q0 = sa, q1 = i_ab, q2 = -i_ab * i_bc * i_ac;
    // and for f = 1/(INV_EPS + sqrt)
    const float ea = rcp_fast(INV_EPS + sa);
    const float eb = rcp_fast(INV_EPS + sb);
    const float ec = rcp_fast(INV_EPS + sc);
    const float g0 = ea;
    const float g1 = -ea * eb * i_ab;
    const float g2 = (INV_EPS + sa + sb + sc) * ea * eb * ec * i_ab * i_bc * i_ac;

    // U = M - l1*I, V = M - l2*I, P = U*V (symmetric since U,V commute)
    const float u00 = m00 - l1, u11 = m11 - l1, u22 = m22 - l1;
    const float v00 = m00 - l2, v11 = m11 - l2, v22 = m22 - l2;
    const float P00 = u00 * v00 + m01 * m01 + m02 * m02;
    const float P01 = u00 * m01 + m01 * v11 + m02 * m12;
    const float P02 = u00 * m02 + m01 * m12 + m02 * v22;
    const float P11 = m01 * m01 + u11 * v11 + m12 * m12;
    const float P12 = m01 * m02 + u11 * m12 + m12 * v22;
    const float P22 = m02 * m02 + m12 * m12 + u22 * v22;

    // A_sqrt (S), A_sqrt_inv (G), both symmetric
    const float S00 = q0 + q1 * u00 + q2 * P00;
    const float S01 =      q1 * m01 + q2 * P01;
    const float S02 =      q1 * m02 + q2 * P02;
    const float S11 = q0 + q1 * u11 + q2 * P11;
    const float S12 =      q1 * m12 + q2 * P12;
    const float S22 = q0 + q1 * u22 + q2 * P22;

    const float G00 = g0 + g1 * u00 + g2 * P00;
    const float G01 =      g1 * m01 + g2 * P01;
    const float G02 =      g1 * m02 + g2 * P02;
    const float G11 = g0 + g1 * u11 + g2 * P11;
    const float G12 =      g1 * m12 + g2 * P12;
    const float G22 = g0 + g1 * u22 + g2 * P22;

    // C = symmetrize(S * c2 * S)
    float T[9];
    T[0] = S00 * c2r[0] + S01 * c2r[3] + S02 * c2r[6];
    T[1] = S00 * c2r[1] + S01 * c2r[4] + S02 * c2r[7];
    T[2] = S00 * c2r[2] + S01 * c2r[5] + S02 * c2r[8];
    T[3] = S01 * c2r[0] + S11 * c2r[3] + S12 * c2r[6];
    T[4] = S01 * c2r[1] + S11 * c2r[4] + S12 * c2r[7];
    T[5] = S01 * c2r[2] + S11 * c2r[5] + S12 * c2r[8];
    T[6] = S02 * c2r[0] + S12 * c2r[3] + S22 * c2r[6];
    T[7] = S02 * c2r[1] + S12 * c2r[4] + S22 * c2r[7];
    T[8] = S02 * c2r[2] + S12 * c2r[5] + S22 * c2r[8];
    float Cf[9];
    Cf[0] = T[0] * S00 + T[1] * S01 + T[2] * S02;
    Cf[1] = T[0] * S01 + T[1] * S11 + T[2] * S12;
    Cf[2] = T[0] * S02 + T[1] * S12 + T[2] * S22;
    Cf[3] = T[3] * S00 + T[4] * S01 + T[5] * S02;
    Cf[4] = T[3] * S01 + T[4] * S11 + T[5] * S12;
    Cf[5] = T[3] * S02 + T[4] * S12 + T[5] * S22;
    Cf[6] = T[6] * S00 + T[7] * S01 + T[8] * S02;
    Cf[7] = T[6] * S01 + T[7] * S11 + T[8] * S12;
    Cf[8] = T[6] * S02 + T[7] * S12 + T[8] * S22;
    const float C00 = Cf[0];
    const float C01 = 0.5f * (Cf[1] + Cf[3]);
    const float C02 = 0.5f * (Cf[2] + Cf[6]);
    const float C11 = Cf[4];
    const float C12 = 0.5f * (Cf[5] + Cf[7]);
    const float C22 = Cf[8];

    // C_sqrt: f(lambda) = sqrt(|lambda|) = (lambda^2)^0.25
    float e1, e2, e3;
    eigvals3(C00, C01, C02, C11, C12, C22, e1, e2, e3);
    const float ra = sqrtf(fabsf(e1));
    const float rb = sqrtf(fabsf(e2));
    const float rc = sqrtf(fabsf(e3));
    const float j_ab = rcp_fast(fmaxf(ra + rb, 1e-12f));
    const float j_bc = rcp_fast(fmaxf(rb + rc, 1e-12f));
    const float j_ac = rcp_fast(fmaxf(ra + rc, 1e-12f));
    const float h0 = ra, h1 = j_ab, h2 = -j_ab * j_bc * j_ac;
    const float cu00 = C00 - e1, cu11 = C11 - e1, cu22 = C22 - e1;
    const float cv00 = C00 - e2, cv11 = C11 - e2, cv22 = C22 - e2;
    const float R00 = cu00 * cv00 + C01 * C01 + C02 * C02;
    const float R01 = cu00 * C01 + C01 * cv11 + C02 * C12;
    const float R02 = cu00 * C02 + C01 * C12 + C02 * cv22;
    const float R11 = C01 * C01 + cu11 * cv11 + C12 * C12;
    const float R12 = C01 * C02 + cu11 * C12 + C12 * cv22;
    const float R22 = C02 * C02 + C12 * C12 + cu22 * cv22;

    const float X00 = h0 + h1 * cu00 + h2 * R00;
    const float X01 =      h1 * C01  + h2 * R01;
    const float X02 =      h1 * C02  + h2 * R02;
    const float X11 = h0 + h1 * cu11 + h2 * R11;
    const float X12 =      h1 * C12  + h2 * R12;
    const float X22 = h0 + h1 * cu22 + h2 * R22;

    // W = S * X * G
    float T2[9];
    T2[0] = S00 * X00 + S01 * X01 + S02 * X02;
    T2[1] = S00 * X01 + S01 * X11 + S02 * X12;
    T2[2] = S00 * X02 + S01 * X12 + S02 * X22;
    T2[3] = S01 * X00 + S11 * X01 + S12 * X02;
    T2[4] = S01 * X01 + S11 * X11 + S12 * X12;
    T2[5] = S01 * X02 + S11 * X12 + S12 * X22;
    T2[6] = S02 * X00 + S12 * X01 + S22 * X02;
    T2[7] = S02 * X01 + S12 * X11 + S22 * X12;
    T2[8] = S02 * X02 + S12 * X12 + S22 * X22;
    float W[9];
    W[0] = T2[0] * G00 + T2[1] * G01 + T2[2] * G02;
    W[1] = T2[0] * G01 + T2[1] * G11 + T2[2] * G12;
    W[2] = T2[0] * G02 + T2[1] * G12 + T2[2] * G22;
    W[3] = T2[3] * G00 + T2[4] * G01 + T2[5] * G02;
    W[4] = T2[3] * G01 + T2[4] * G11 + T2[5] * G12;
    W[5] = T2[3] * G02 + T2[4] * G12 + T2[5] * G22;
    W[6] = T2[6] * G00 + T2[7] * G01 + T2[8] * G02;
    W[7] = T2[6] * G01 + T2[7] * G11 + T2[8] * G12;
    W[8] = T2[6] * G02 + T2[7] * G12 + T2[8] * G22;

    // cov_vel = W + W^T - (cov_1 + cov_1^T);  cov_1 + cov_1^T == 2*M1
    const float M1f[9] = { m00, m01, m02, m01, m11, m12, m02, m12, m22 };
    float* out_miu = out;
    float* out_cov = out + (size_t)N * 3;
    float* oc = out_cov + (size_t)i * 9;
    #pragma unroll
    for (int r = 0; r < 3; ++r)
        #pragma unroll
        for (int cidx = 0; cidx < 3; ++cidx)
            oc[r * 3 + cidx] = ok ? (W[r * 3 + cidx] + W[cidx * 3 + r] - 2.0f * M1f[r * 3 + cidx])
                                  : 0.0f;
    float* om = out_miu + (size_t)i * 3;
    #pragma unroll
    for (int k = 0; k < 3; ++k) om[k] = ok ? (u2[k] - u1[k]) : 0.0f;
}

} // namespace

extern "C" void kernel_launch(void* const* d_in, const int* in_sizes, int n_in,
                              void* d_out, int out_size, void* d_ws, size_t ws_size,
                              hipStream_t stream)
{
    const float* miu1 = (const float*)d_in[0];
    const float* miu2 = (const float*)d_in[1];
    const float* cov1 = (const float*)d_in[2];
    const float* cov2 = (const float*)d_in[3];
    float* out = (float*)d_out;
    const int N = in_sizes[0] / 3;
    const int grid = (N + BS - 1) / BS;
    hipLaunchKernelGGL(wl_kernel, dim3(grid), dim3(BS), 0, stream,
                       miu1, miu2, cov1, cov2, out, N);
}

// Round 3
// 28.610 us; speedup vs baseline: 1.3927x; 1.0389x over previous
//
#include <hip/hip_runtime.h>
#include <math.h>

#define MAX_COV 10000.0f
#define MIN_COV 0.0001f
#define SYMM_THRESH 1e-05f
#define DET_THRESH 1e-06f
#define MAX_POS 1000.0f
#define EIG_CLAMP 0.0001f
#define INV_EPS 0.0001f

namespace {
constexpr int BS = 256;

__device__ __forceinline__ float rcp_fast(float x)  { return __builtin_amdgcn_rcpf(x); }
__device__ __forceinline__ float sqrt_fast(float x) { return __builtin_amdgcn_sqrtf(x); }

// acos via A&S 4.4.45: |err| <= ~7e-5 rad, branchless.
__device__ __forceinline__ float acos_fast(float x) {
    const float t = fabsf(x);
    const float s = sqrt_fast(fmaxf(1.0f - t, 0.0f));
    float p = fmaf(t, -0.0187293f, 0.0742610f);
    p = fmaf(t, p, -0.2121144f);
    p = fmaf(t, p, 1.5707288f);
    const float a = s * p;
    return (x >= 0.0f) ? a : (3.14159265358979f - a);
}

// Closed-form eigenvalues of a symmetric 3x3 (trig method).
__device__ __forceinline__ void eigvals3(
    float m00, float m01, float m02, float m11, float m12, float m22,
    float& l1, float& l2, float& l3)
{
    const float q   = (m00 + m11 + m22) * (1.0f / 3.0f);
    const float b00 = m00 - q, b11 = m11 - q, b22 = m22 - q;
    const float offsq = m01 * m01 + m02 * m02 + m12 * m12;
    const float p2  = b00 * b00 + b11 * b11 + b22 * b22 + 2.0f * offsq;
    const float p   = sqrt_fast(p2 * (1.0f / 6.0f));
    const float detB =
          b00 * (b11 * b22 - m12 * m12)
        - m01 * (m01 * b22 - m12 * m02)
        + m02 * (m01 * m12 - b11 * m02);
    const float pinv = rcp_fast(fmaxf(p, 1e-30f));
    // left-to-right order: detB==0 with p==0 must give 0, not NaN
    float r = 0.5f * detB;
    r = r * pinv; r = r * pinv; r = r * pinv;
    r = fminf(1.0f, fmaxf(-1.0f, r));
    const float phi = acos_fast(r) * (1.0f / 3.0f);    // [0, pi/3]
    const float c   = __cosf(phi);
    const float s   = sqrt_fast(fmaxf(1.0f - c * c, 0.0f));
    l1 = q + 2.0f * p * c;
    l3 = q + p * (-c - 1.7320508075688772f * s);       // cos(phi+2pi/3) identity
    l2 = 3.0f * q - l1 - l3;
}

__global__ __launch_bounds__(BS, 4)
void wl_kernel(const float* __restrict__ miu1, const float* __restrict__ miu2,
               const float* __restrict__ cov1, const float* __restrict__ cov2,
               float* __restrict__ out, int N)
{
    const int i = blockIdx.x * BS + threadIdx.x;
    if (i >= N) return;

    float c1[9], c2r[9], u1[3], u2[3];
    {
        const float* p1 = cov1 + (size_t)i * 9;
        const float* p2 = cov2 + (size_t)i * 9;
        #pragma unroll
        for (int k = 0; k < 9; ++k) { c1[k] = p1[k]; c2r[k] = p2[k]; }
        const float* q1p = miu1 + (size_t)i * 3;
        const float* q2p = miu2 + (size_t)i * 3;
        #pragma unroll
        for (int k = 0; k < 3; ++k) { u1[k] = q1p[k]; u2[k] = q2p[k]; }
    }

    // ---- stability mask ----
    // abs-range via max/min chains (abs() is a free VALU input modifier).
    // NaN handling: v_max/v_min drop NaN, but any NaN in cov makes det=NaN
    // -> fabsf(det)>THRESH is false -> masked. miu NaN caught by its compare.
    float amax1 = 0.0f, amax2 = 0.0f, amin1 = 1e30f, amin2 = 1e30f;
    #pragma unroll
    for (int k = 0; k < 9; ++k) {
        amax1 = fmaxf(amax1, fabsf(c1[k]));  amin1 = fminf(amin1, fabsf(c1[k]));
        amax2 = fmaxf(amax2, fabsf(c2r[k])); amin2 = fminf(amin2, fabsf(c2r[k]));
    }
    bool ok = (amax1 < MAX_COV) && (amax2 < MAX_COV)
           && (amin1 > MIN_COV) && (amin2 > MIN_COV);
    const float sd = fmaxf(fmaxf(fabsf(c1[1] - c1[3]), fabsf(c1[2] - c1[6])),
                    fmaxf(fabsf(c1[5] - c1[7]),
                    fmaxf(fmaxf(fabsf(c2r[1] - c2r[3]), fabsf(c2r[2] - c2r[6])),
                          fabsf(c2r[5] - c2r[7]))));
    ok = ok && (sd < SYMM_THRESH);
    const float det1 = c1[0] * (c1[4] * c1[8] - c1[5] * c1[7])
                     - c1[1] * (c1[3] * c1[8] - c1[5] * c1[6])
                     + c1[2] * (c1[3] * c1[7] - c1[4] * c1[6]);
    const float det2 = c2r[0] * (c2r[4] * c2r[8] - c2r[5] * c2r[7])
                     - c2r[1] * (c2r[3] * c2r[8] - c2r[5] * c2r[6])
                     + c2r[2] * (c2r[3] * c2r[7] - c2r[4] * c2r[6]);
    ok = ok && (fabsf(det1) > DET_THRESH) && (fabsf(det2) > DET_THRESH);
    const float um = fmaxf(fmaxf(fmaxf(fabsf(u1[0]), fabsf(u1[1])), fabsf(u1[2])),
                           fmaxf(fmaxf(fabsf(u2[0]), fabsf(u2[1])), fabsf(u2[2])));
    ok = ok && (um < MAX_POS);

    // ---- symmetrized inputs; masked items -> identity ----
    const float m00 = ok ? c1[0] : 1.0f;
    const float m01 = ok ? (0.5f * (c1[1] + c1[3])) : 0.0f;
    const float m02 = ok ? (0.5f * (c1[2] + c1[6])) : 0.0f;
    const float m11 = ok ? c1[4] : 1.0f;
    const float m12 = ok ? (0.5f * (c1[5] + c1[7])) : 0.0f;
    const float m22 = ok ? c1[8] : 1.0f;
    // sym(S*c2*S) == S*sym(c2)*S exactly (S symmetric), so symmetrize c2 now.
    const float d00 = ok ? c2r[0] : 1.0f;
    const float d01 = ok ? (0.5f * (c2r[1] + c2r[3])) : 0.0f;
    const float d02 = ok ? (0.5f * (c2r[2] + c2r[6])) : 0.0f;
    const float d11 = ok ? c2r[4] : 1.0f;
    const float d12 = ok ? (0.5f * (c2r[5] + c2r[7])) : 0.0f;
    const float d22 = ok ? c2r[8] : 1.0f;

    float l1, l2, l3;
    eigvals3(m00, m01, m02, m11, m12, m22, l1, l2, l3);
    l1 = fmaxf(l1, EIG_CLAMP); l2 = fmaxf(l2, EIG_CLAMP); l3 = fmaxf(l3, EIG_CLAMP);
    const float sa = sqrt_fast(l1), sb = sqrt_fast(l2), sc = sqrt_fast(l3);
    const float i_ab = rcp_fast(sa + sb);
    const float i_bc = rcp_fast(sb + sc);
    const float i_ac = rcp_fast(sa + sc);
    // Newton-form coefficients for f=sqrt at nodes (l1,l2,l3)
    const float q0 = sa, q1 = i_ab, q2 = -i_ab * i_bc * i_ac;
    // and for f = 1/(INV_EPS + sqrt)
    const float ea = rcp_fast(INV_EPS + sa);
    const float eb = rcp_fast(INV_EPS + sb);
    const float ec = rcp_fast(INV_EPS + sc);
    const float g0 = ea;
    const float g1 = -ea * eb * i_ab;
    const float g2 = (INV_EPS + sa + sb + sc) * ea * eb * ec * i_ab * i_bc * i_ac;

    // U = M - l1*I, V = M - l2*I, P = U*V (symmetric)
    const float u00 = m00 - l1, u11 = m11 - l1, u22 = m22 - l1;
    const float v00 = m00 - l2, v11 = m11 - l2, v22 = m22 - l2;
    const float P00 = u00 * v00 + m01 * m01 + m02 * m02;
    const float P01 = u00 * m01 + m01 * v11 + m02 * m12;
    const float P02 = u00 * m02 + m01 * m12 + m02 * v22;
    const float P11 = m01 * m01 + u11 * v11 + m12 * m12;
    const float P12 = m01 * m02 + u11 * m12 + m12 * v22;
    const float P22 = m02 * m02 + m12 * m12 + u22 * v22;

    // A_sqrt (S), A_sqrt_inv (G), both symmetric
    const float S00 = q0 + q1 * u00 + q2 * P00;
    const float S01 =      q1 * m01 + q2 * P01;
    const float S02 =      q1 * m02 + q2 * P02;
    const float S11 = q0 + q1 * u11 + q2 * P11;
    const float S12 =      q1 * m12 + q2 * P12;
    const float S22 = q0 + q1 * u22 + q2 * P22;

    const float G00 = g0 + g1 * u00 + g2 * P00;
    const float G01 =      g1 * m01 + g2 * P01;
    const float G02 =      g1 * m02 + g2 * P02;
    const float G11 = g0 + g1 * u11 + g2 * P11;
    const float G12 =      g1 * m12 + g2 * P12;
    const float G22 = g0 + g1 * u22 + g2 * P22;

    // C = S*D*S (exactly symmetric now): T = S*D full, then upper triangle of T*S
    const float T00 = S00 * d00 + S01 * d01 + S02 * d02;
    const float T01 = S00 * d01 + S01 * d11 + S02 * d12;
    const float T02 = S00 * d02 + S01 * d12 + S02 * d22;
    const float T10 = S01 * d00 + S11 * d01 + S12 * d02;
    const float T11 = S01 * d01 + S11 * d11 + S12 * d12;
    const float T12 = S01 * d02 + S11 * d12 + S12 * d22;
    const float T20 = S02 * d00 + S12 * d01 + S22 * d02;
    const float T21 = S02 * d01 + S12 * d11 + S22 * d12;
    const float T22m = S02 * d02 + S12 * d12 + S22 * d22;
    const float C00 = T00 * S00 + T01 * S01 + T02 * S02;
    const float C01 = T00 * S01 + T01 * S11 + T02 * S12;
    const float C02 = T00 * S02 + T01 * S12 + T02 * S22;
    const float C11 = T10 * S01 + T11 * S11 + T12 * S12;
    const float C12 = T10 * S02 + T11 * S12 + T12 * S22;
    const float C22 = T20 * S02 + T21 * S12 + T22m * S22;

    // C_sqrt: f(lambda) = sqrt(|lambda|)
    float e1, e2, e3;
    eigvals3(C00, C01, C02, C11, C12, C22, e1, e2, e3);
    const float ra = sqrt_fast(fabsf(e1));
    const float rb = sqrt_fast(fabsf(e2));
    const float rc = sqrt_fast(fabsf(e3));
    const float j_ab = rcp_fast(fmaxf(ra + rb, 1e-12f));
    const float j_bc = rcp_fast(fmaxf(rb + rc, 1e-12f));
    const float j_ac = rcp_fast(fmaxf(ra + rc, 1e-12f));
    const float h0 = ra, h1 = j_ab, h2 = -j_ab * j_bc * j_ac;
    const float cu00 = C00 - e1, cu11 = C11 - e1, cu22 = C22 - e1;
    const float cv00 = C00 - e2, cv11 = C11 - e2, cv22 = C22 - e2;
    const float R00 = cu00 * cv00 + C01 * C01 + C02 * C02;
    const float R01 = cu00 * C01 + C01 * cv11 + C02 * C12;
    const float R02 = cu00 * C02 + C01 * C12 + C02 * cv22;
    const float R11 = C01 * C01 + cu11 * cv11 + C12 * C12;
    const float R12 = C01 * C02 + cu11 * C12 + C12 * cv22;
    const float R22 = C02 * C02 + C12 * C12 + cu22 * cv22;

    const float X00 = h0 + h1 * cu00 + h2 * R00;
    const float X01 =      h1 * C01  + h2 * R01;
    const float X02 =      h1 * C02  + h2 * R02;
    const float X11 = h0 + h1 * cu11 + h2 * R11;
    const float X12 =      h1 * C12  + h2 * R12;
    const float X22 = h0 + h1 * cu22 + h2 * R22;

    // W = S * X * G
    const float A00 = S00 * X00 + S01 * X01 + S02 * X02;
    const float A01 = S00 * X01 + S01 * X11 + S02 * X12;
    const float A02 = S00 * X02 + S01 * X12 + S02 * X22;
    const float A10 = S01 * X00 + S11 * X01 + S12 * X02;
    const float A11 = S01 * X01 + S11 * X11 + S12 * X12;
    const float A12 = S01 * X02 + S11 * X12 + S12 * X22;
    const float A20 = S02 * X00 + S12 * X01 + S22 * X02;
    const float A21 = S02 * X01 + S12 * X11 + S22 * X12;
    const float A22 = S02 * X02 + S12 * X12 + S22 * X22;
    float W[9];
    W[0] = A00 * G00 + A01 * G01 + A02 * G02;
    W[1] = A00 * G01 + A01 * G11 + A02 * G12;
    W[2] = A00 * G02 + A01 * G12 + A02 * G22;
    W[3] = A10 * G00 + A11 * G01 + A12 * G02;
    W[4] = A10 * G01 + A11 * G11 + A12 * G12;
    W[5] = A10 * G02 + A11 * G12 + A12 * G22;
    W[6] = A20 * G00 + A21 * G01 + A22 * G02;
    W[7] = A20 * G01 + A21 * G11 + A22 * G12;
    W[8] = A20 * G02 + A21 * G12 + A22 * G22;

    // cov_vel = W + W^T - 2*sym(cov_1)
    const float M1f[9] = { m00, m01, m02, m01, m11, m12, m02, m12, m22 };
    float* out_miu = out;
    float* out_cov = out + (size_t)N * 3;
    float* oc = out_cov + (size_t)i * 9;
    #pragma unroll
    for (int r = 0; r < 3; ++r)
        #pragma unroll
        for (int cidx = 0; cidx < 3; ++cidx)
            oc[r * 3 + cidx] = ok ? (W[r * 3 + cidx] + W[cidx * 3 + r] - 2.0f * M1f[r * 3 + cidx])
                                  : 0.0f;
    float* om = out_miu + (size_t)i * 3;
    #pragma unroll
    for (int k = 0; k < 3; ++k) om[k] = ok ? (u2[k] - u1[k]) : 0.0f;
}

} // namespace

extern "C" void kernel_launch(void* const* d_in, const int* in_sizes, int n_in,
                              void* d_out, int out_size, void* d_ws, size_t ws_size,
                              hipStream_t stream)
{
    const float* miu1 = (const float*)d_in[0];
    const float* miu2 = (const float*)d_in[1];
    const float* cov1 = (const float*)d_in[2];
    const float* cov2 = (const float*)d_in[3];
    float* out = (float*)d_out;
    const int N = in_sizes[0] / 3;
    const int grid = (N + BS - 1) / BS;
    hipLaunchKernelGGL(wl_kernel, dim3(grid), dim3(BS), 0, stream,
                       miu1, miu2, cov1, cov2, out, N);
}